// Round 3
// baseline (236.597 us; speedup 1.0000x reference)
//
#include <hip/hip_runtime.h>
#include <math.h>

// Problem constants
#define BB     512
#define INF    256
#define CONDF  128
#define NEXP   8
#define HDIM   64
#define TPE    49280      // IN*DP + IN*DN + DN
#define TOTC   394240     // N*TPE
#define NSPLIT 16
#define CW     1536       // GEMM columns: 8 experts * (64 wp + 128 wn)
#define KB     261        // K blocks of 64: 64*4 main + 5 tail (16704 total K)

// Workspace layout (bytes). Total ~43.3 MB.
#define AZ_OFF  0u                    // ushort [261][512][64]  = 17,104,896
#define BTS_OFF 17104896u             // ushort [5][1536][64]   = 983,040 (tail kbs only)
#define P_OFF   18087936u             // ushort [16][512][1536] = 25,165,824 (bf16 partials)
#define GW_OFF  43253760u             // float  [512][8]
#define CB_OFF  43270144u             // float  [1536]

typedef __bf16          bf16x8 __attribute__((ext_vector_type(8)));
typedef unsigned short  us8    __attribute__((ext_vector_type(8)));
typedef float           f32x4  __attribute__((ext_vector_type(4)));

__device__ __forceinline__ unsigned short f2bf(float f) {
  unsigned u = __builtin_bit_cast(unsigned, f);
  u += 0x7fffu + ((u >> 16) & 1u);           // RNE
  return (unsigned short)(u >> 16);
}
__device__ __forceinline__ float bf2f(unsigned short u) {
  return __builtin_bit_cast(float, ((unsigned)u) << 16);
}

__device__ __forceinline__ void gld16(const void* g, const void* l) {
  __builtin_amdgcn_global_load_lds(
      (const __attribute__((address_space(1))) unsigned int*)g,
      (__attribute__((address_space(3))) unsigned int*)l, 16, 0, 0);
}

// ---------------- K_prep:
//   blocks   0..511 : per-sample prep (h, gates, Az rows incl. tail kbs)
//   blocks 512..535 : base-weight tail transpose (bwp/bwn + hb2) -> Bts idx 0..3
//   blocks 536..543 : Bts idx 4 (bias-delta row) + zero cols + colbias (one per ne)
__global__ __launch_bounds__(256, 4)
void k_prep(const float* __restrict__ hW2, unsigned short* __restrict__ Bts,
            const float* __restrict__ bwp, const float* __restrict__ bwn,
            const float* __restrict__ bbn, const float* __restrict__ hb2,
            float* __restrict__ colbias,
            const float* __restrict__ x, const float* __restrict__ cond,
            const float* __restrict__ hW1, const float* __restrict__ hb1,
            const float* __restrict__ gW1, const float* __restrict__ gb1,
            const float* __restrict__ gW2, const float* __restrict__ gb2,
            unsigned short* __restrict__ Az, float* __restrict__ gw) {
  const int bx = blockIdx.x;
  const int tid = threadIdx.x;          // 256
  __shared__ __align__(16) unsigned short Ls[64 * 256];   // 32 KiB, reused by all paths

  if (bx < 512) {                       // ---- prep path (one block per sample)
    const int b = bx;
    float* xs  = (float*)Ls;            // 256
    float* cs  = xs + INF;              // 128
    float* hs  = cs + CONDF;            // 64
    float* g1  = hs + HDIM;             // 24
    float* lsb = g1 + 24;               // 8
    float* es  = lsb + 8;               // 8
    xs[tid] = x[b * INF + tid];
    if (tid < CONDF) cs[tid] = cond[b * CONDF + tid];
    __syncthreads();
    if (tid < HDIM) {
      float acc = hb1[tid];
      for (int q = 0; q < CONDF; ++q) acc = fmaf(cs[q], hW1[q * HDIM + tid], acc);
      hs[tid] = fmaxf(acc, 0.f);
    }
    if (tid >= 64 && tid < 88) {
      const int r = tid - 64;
      float acc = gb1[r];
      for (int q = 0; q < CONDF; ++q) acc = fmaf(cs[q], gW1[q * 24 + r], acc);
      g1[r] = fmaxf(acc, 0.f);
    }
    __syncthreads();
    if (tid < NEXP) {
      float acc = gb2[tid];
      for (int j = 0; j < 24; ++j) acc = fmaf(g1[j], gW2[j * NEXP + tid], acc);
      lsb[tid] = acc;
    }
    __syncthreads();
    if (tid < NEXP) {
      float m = lsb[0];
      for (int j = 1; j < NEXP; ++j) m = fmaxf(m, lsb[j]);
      es[tid] = expf(lsb[tid] - m);
    }
    __syncthreads();
    if (tid < NEXP) {
      float s = 0.f;
      for (int j = 0; j < NEXP; ++j) s += es[j];
      gw[b * NEXP + tid] = es[tid] / s;
    }
    // z writes: 8 t-groups x 32 i-octets
    const int t0 = tid >> 5, ig = tid & 31;
#pragma unroll
    for (int tt = 0; tt < 8; ++tt) {
      const int t = tt * 8 + t0;
      const float hv = hs[t];
      us8 o;
#pragma unroll
      for (int j = 0; j < 8; ++j) o[j] = f2bf(hv * xs[ig * 8 + j]);
      *(us8*)(Az + ((size_t)(t * 4 + (ig >> 3)) * BB + b) * 64 + (ig & 7) * 8) = o;
    }
    // tail rows: kb 256..259 = x, kb 260 = h
    Az[((size_t)(256 + (tid >> 6)) * BB + b) * 64 + (tid & 63)] = f2bf(xs[tid]);
    if (tid < HDIM) Az[((size_t)260 * BB + b) * 64 + tid] = f2bf(hs[tid]);
    return;
  }

  if (bx >= 536) {                      // ---- Bts idx 4 + zeros + colbias (one per ne)
    const int ne = bx - 536;
    unsigned short* L2 = Ls;            // [64][129]
#pragma unroll
    for (int it = 0; it < 8; ++it) {
      const int f = it * 256 + tid;     // 2048 f32x4 = 8192 floats
      const int t = f >> 5, c4 = (f & 31) * 4;
      f32x4 v = *(const f32x4*)(hW2 + (size_t)t * TOTC + (size_t)ne * TPE + 49152 + c4);
#pragma unroll
      for (int j = 0; j < 4; ++j) L2[t * 129 + c4 + j] = f2bf(v[j]);
    }
    if (tid < 192)
      colbias[ne * 192 + tid] = (tid < 64) ? 0.f
        : bbn[ne * 128 + (tid - 64)] + hb2[(size_t)ne * TPE + 49152 + (tid - 64)];
    __syncthreads();
    if (tid < 128) {                    // wn cols
      const int c = tid;
#pragma unroll
      for (int t8 = 0; t8 < 8; ++t8) {
        us8 o;
#pragma unroll
        for (int j = 0; j < 8; ++j) o[j] = L2[(t8 * 8 + j) * 129 + c];
        *(us8*)(Bts + ((size_t)4 * CW + ne * 192 + 64 + c) * 64 + t8 * 8) = o;
      }
    } else {                            // wp cols: zeros
      const int cz = (tid - 128) >> 1, hf = (tid - 128) & 1;
      us8 z = (us8){0, 0, 0, 0, 0, 0, 0, 0};
#pragma unroll
      for (int t8 = 0; t8 < 4; ++t8)
        *(us8*)(Bts + ((size_t)4 * CW + ne * 192 + cz) * 64 + (hf * 4 + t8) * 8) = z;
    }
    return;
  }

  // ---- tail transpose: bwp/bwn + hb2 -> Bts idx 0..3
  const int pq = tid & 15, rg = tid >> 4, p4 = pq * 4;
  const int u = bx - 512, ne = u / 3, sec = u % 3;
  const int dst  = sec ? 128 : 64;
  const int poff = (sec == 2) ? 64 : 0;
  const int cbase = ne * 192 + sec * 64;
  const float* s1 = sec ? (bwn + (size_t)ne * INF * 128 + poff)
                        : (bwp + (size_t)ne * INF * 64);
  const float* s2 = hb2 + (size_t)ne * TPE + (sec ? 16384 : 0) + poff;
#pragma unroll
  for (int it = 0; it < 8; ++it) {
    const int i0 = rg * 2 + it * 32;
    f32x4 a1 = *(const f32x4*)(s1 + (size_t)i0 * dst + p4);
    f32x4 a2 = *(const f32x4*)(s2 + (size_t)i0 * dst + p4);
    f32x4 b1 = *(const f32x4*)(s1 + (size_t)(i0 + 1) * dst + p4);
    f32x4 b2 = *(const f32x4*)(s2 + (size_t)(i0 + 1) * dst + p4);
    const int e = i0 >> 3, q0 = i0 & 7;
#pragma unroll
    for (int j = 0; j < 4; ++j) {
      const int p = p4 + j;
      const unsigned lo = f2bf(a1[j] + a2[j]);
      const unsigned hi = f2bf(b1[j] + b2[j]);
      *(unsigned*)(&Ls[(p << 8) + (((e ^ (p >> 2)) << 3) | q0)]) = lo | (hi << 16);
    }
  }
  __syncthreads();
  us8 o[8];
#pragma unroll
  for (int it2 = 0; it2 < 8; ++it2) {
    const int of = it2 * 256 + tid;
    const int p = of >> 5, seg = of & 31;
    o[it2] = *(const us8*)(&Ls[(p << 8) + ((seg ^ (p >> 2)) << 3)]);
  }
#pragma unroll
  for (int it2 = 0; it2 < 8; ++it2) {
    const int of = it2 * 256 + tid;
    const int p = of >> 5, seg = of & 31, ib = seg >> 3, k8 = seg & 7;
    *(us8*)(Bts + ((size_t)ib * CW + cbase + p) * 64 + k8 * 8) = o[it2];
  }
}

// ---------------- K3: split-K MFMA GEMM with FUSED B transpose from hW2.
// Block 128m x 128n, 768 blocks = 3/CU.  XCD swizzle co-locates the 4 m-blocks
// of each (nt,s) group -> hW2 tile fetched once per XCD, served from L2 for mt>0.
// Main kbs (<256): reg-stage 64x128 f32 from hW2, convert, ds_write_b32 into
// the SAME swizzled Bs layout (octet g of row r at slot g^(r&7)) the MFMA reads.
// Tail kbs (256..260): gld16 from the small Bts built by k_prep.
__launch_bounds__(256, 3)
__global__ void k_gemm(const unsigned short* __restrict__ Az,
                       const float* __restrict__ hW2,
                       const unsigned short* __restrict__ Bts,
                       unsigned short* __restrict__ P) {
  const int bid = blockIdx.x;           // 0..767
  const int g  = (bid >> 5) * 8 + (bid & 7);
  const int mt = (bid >> 3) & 3;
  const int nt = g >> 4;                // 0..11
  const int s  = g & 15;                // 0..15
  const int m0 = mt * 128, n0 = nt * 128;
  // balanced split-K: first 5 splits take 17 kbs, rest 16  (5*17 + 11*16 = 261)
  const int kb0 = s * 16 + (s < 5 ? s : 5);
  const int kb1 = kb0 + 16 + (s < 5 ? 1 : 0);
  const int tid = threadIdx.x;
  __shared__ __align__(16) unsigned short As[128 * 64];
  __shared__ __align__(16) unsigned short Bs[128 * 64];

  f32x4 acc[4][4];
#pragma unroll
  for (int mi = 0; mi < 4; ++mi)
#pragma unroll
    for (int ni = 0; ni < 4; ++ni) acc[mi][ni] = (f32x4){0.f, 0.f, 0.f, 0.f};

  const int wv = tid >> 6, lane = tid & 63;
  const int wm = wv >> 1, wn = wv & 1;
  const int lrow = lane & 15, quad = lane >> 4;
  const int srow = tid >> 3;            // 0..31
  const int sg0  = tid & 7;

  // B-staging thread constants: (half, m, pi) partition of 256 threads.
  // Within a 16-lane phase only m&1 (2 vals) and pi&3 (4 vals) vary ->
  // 8 distinct banks x 2 lanes = 2-way LDS writes (free).
  const int half = tid >> 7;            // 0..1  (64-col half of the n-tile)
  const int mq   = (tid >> 3) & 15;     // 0..15 (16B col group within half)
  const int pi   = tid & 7;             // 0..7  (k row pair)
  const int ch   = n0 + half * 64;      // 64-col halves never cross wp/wn seams
  const int neb  = ch / 192;
  const int r0   = ch - neb * 192;
  const int wp   = (r0 < 64);
  const int sh   = wp ? 6 : 7;          // row stride log2 (64 or 128 floats)
  const float* Bh = hW2 + (size_t)(neb * TPE + (wp ? r0 : 16384 + (r0 - 64)) + mq * 4);
  const int rbase = half * 64 + mq * 4; // Bs row base for this thread's 4 cols

  for (int kb = kb0; kb < kb1; ++kb) {
    // ---- A stage (async global->LDS, pre-swizzled source)
    const unsigned short* ab = Az + ((size_t)kb * BB + m0) * 64;
#pragma unroll
    for (int it = 0; it < 4; ++it) {
      const int r = it * 32 + srow;
      const int ga = sg0 ^ (r & 7);
      const int ldsoff = __builtin_amdgcn_readfirstlane(it * 4096 + wv * 1024);
      gld16(ab + (size_t)r * 64 + ga * 8, (const char*)As + ldsoff);
    }
    // ---- B stage
    if (kb < 256) {                     // fused transpose from hW2
      const float* Br = Bh + (size_t)(kb >> 2) * TOTC;
      const int i0 = (kb & 3) * 64;
      f32x4 va[4], vb[4];
#pragma unroll
      for (int it = 0; it < 4; ++it) {
        const int ko = pi * 2 + it * 16;
        va[it] = *(const f32x4*)(Br + ((i0 + ko) << sh));
        vb[it] = *(const f32x4*)(Br + ((i0 + ko + 1) << sh));
      }
#pragma unroll
      for (int it = 0; it < 4; ++it) {
        const int gg = (pi >> 2) + it * 2;       // k octet index
#pragma unroll
        for (int j = 0; j < 4; ++j) {
          const int rl = rbase + j;              // Bs row (= GEMM col - n0)
          const unsigned lo = f2bf(va[it][j]), hi = f2bf(vb[it][j]);
          *(unsigned*)((char*)Bs + rl * 128 + ((gg ^ (rl & 7)) << 4) + ((pi & 3) << 2))
              = lo | (hi << 16);
        }
      }
    } else {                            // tail kbs from small Bts
      const unsigned short* bbp = Bts + ((size_t)(kb - 256) * CW + n0) * 64;
#pragma unroll
      for (int it = 0; it < 4; ++it) {
        const int r = it * 32 + srow;
        const int ga = sg0 ^ (r & 7);
        const int ldsoff = __builtin_amdgcn_readfirstlane(it * 4096 + wv * 1024);
        gld16(bbp + (size_t)r * 64 + ga * 8, (const char*)Bs + ldsoff);
      }
    }
    __syncthreads();
#pragma unroll
    for (int kh = 0; kh < 2; ++kh) {
      bf16x8 af[4], bfr[4];
#pragma unroll
      for (int mi = 0; mi < 4; ++mi) {
        const int r = wm * 64 + mi * 16 + lrow;
        const int ga = (kh * 4 + quad) ^ (r & 7);
        af[mi] = *(const bf16x8*)(As + r * 64 + ga * 8);
      }
#pragma unroll
      for (int ni = 0; ni < 4; ++ni) {
        const int r = wn * 64 + ni * 16 + lrow;
        const int ga = (kh * 4 + quad) ^ (r & 7);
        bfr[ni] = *(const bf16x8*)(Bs + r * 64 + ga * 8);
      }
#pragma unroll
      for (int mi = 0; mi < 4; ++mi)
#pragma unroll
        for (int ni = 0; ni < 4; ++ni)
          acc[mi][ni] = __builtin_amdgcn_mfma_f32_16x16x32_bf16(af[mi], bfr[ni], acc[mi][ni], 0, 0, 0);
    }
    __syncthreads();
  }

  // write bf16 partials: D row = quad*4+reg, col = lane&15
#pragma unroll
  for (int mi = 0; mi < 4; ++mi) {
    const int row0 = m0 + wm * 64 + mi * 16 + quad * 4;
#pragma unroll
    for (int ni = 0; ni < 4; ++ni) {
      const int col = n0 + wn * 64 + ni * 16 + lrow;
      unsigned short* pp = P + ((size_t)s * BB + row0) * CW + col;
#pragma unroll
      for (int r = 0; r < 4; ++r) pp[(size_t)r * CW] = f2bf(acc[mi][ni][r]);
    }
  }
}

// ---------------- K4: epilogue — sum bf16 split-K partials, cos/sin/relu, gated expert sum
__global__ void k_epi(const unsigned short* __restrict__ P, const float* __restrict__ gw,
                      const float* __restrict__ colbias, float* __restrict__ out) {
  const int b = blockIdx.x;
  const int r = threadIdx.x;            // 192: wave0 = wp cols, waves1-2 = wn cols
  __shared__ float gws[NEXP];
  if (r < NEXP) gws[r] = gw[b * NEXP + r];
  __syncthreads();
  float co = 0.f, si = 0.f, nc = 0.f;
  for (int n = 0; n < NEXP; ++n) {
    const int c = n * 192 + r;
    float v = colbias[c];
#pragma unroll
    for (int s2 = 0; s2 < NSPLIT; ++s2) v += bf2f(P[((size_t)s2 * BB + b) * CW + c]);
    const float g = gws[n];
    if (r < 64) { co = fmaf(g, cosf(v), co); si = fmaf(g, sinf(v), si); }
    else        { nc = fmaf(g, fmaxf(v, 0.f), nc); }
  }
  if (r < 64) { out[b * 256 + r] = co; out[b * 256 + 64 + r] = si; }
  else        { out[b * 256 + 128 + (r - 64)] = nc; }
}

extern "C" void kernel_launch(void* const* d_in, const int* in_sizes, int n_in,
                              void* d_out, int out_size, void* d_ws, size_t ws_size,
                              hipStream_t stream) {
  const float* x    = (const float*)d_in[0];
  const float* cond = (const float*)d_in[1];
  const float* bwp  = (const float*)d_in[2];
  const float* bwn  = (const float*)d_in[3];
  const float* bbn  = (const float*)d_in[4];
  const float* hW1  = (const float*)d_in[5];
  const float* hb1  = (const float*)d_in[6];
  const float* hW2  = (const float*)d_in[7];
  const float* hb2  = (const float*)d_in[8];
  const float* gW1  = (const float*)d_in[9];
  const float* gb1  = (const float*)d_in[10];
  const float* gW2  = (const float*)d_in[11];
  const float* gb2  = (const float*)d_in[12];
  float* out = (float*)d_out;
  char* ws = (char*)d_ws;

  unsigned short* Az  = (unsigned short*)(ws + AZ_OFF);
  unsigned short* Bts = (unsigned short*)(ws + BTS_OFF);
  unsigned short* Pp  = (unsigned short*)(ws + P_OFF);
  float* gw      = (float*)(ws + GW_OFF);
  float* colbias = (float*)(ws + CB_OFF);

  hipLaunchKernelGGL(k_prep, dim3(544), dim3(256), 0, stream,
                     hW2, Bts, bwp, bwn, bbn, hb2, colbias,
                     x, cond, hW1, hb1, gW1, gb1, gW2, gb2, Az, gw);
  hipLaunchKernelGGL(k_gemm, dim3(768), dim3(256), 0, stream, Az, hW2, Bts, Pp);
  hipLaunchKernelGGL(k_epi, dim3(BB), dim3(192), 0, stream, Pp, gw, colbias, out);
}

// Round 4
// 230.017 us; speedup vs baseline: 1.0286x; 1.0286x over previous
//
#include <hip/hip_runtime.h>
#include <math.h>

// Problem constants
#define BB     512
#define INF    256
#define CONDF  128
#define NEXP   8
#define HDIM   64
#define TPE    49280      // IN*DP + IN*DN + DN
#define TOTC   394240     // N*TPE
#define NSPLIT 16
#define CW     1536       // GEMM columns: 8 experts * (64 wp + 128 wn)
#define KB     261        // K blocks of 64: 64*4 main + 5 tail (16704 total K)

// Workspace layout (bytes). Total ~43.3 MB.
#define AZ_OFF  0u                    // ushort [261][512][64]  = 17,104,896
#define BTS_OFF 17104896u             // ushort [5][1536][64]   = 983,040 (tail kbs only)
#define P_OFF   18087936u             // ushort [16][512][1536] = 25,165,824 (bf16 partials)
#define GW_OFF  43253760u             // float  [512][8]
#define CB_OFF  43270144u             // float  [1536]

typedef __bf16          bf16x8 __attribute__((ext_vector_type(8)));
typedef unsigned short  us8    __attribute__((ext_vector_type(8)));
typedef float           f32x4  __attribute__((ext_vector_type(4)));

__device__ __forceinline__ unsigned short f2bf(float f) {
  unsigned u = __builtin_bit_cast(unsigned, f);
  u += 0x7fffu + ((u >> 16) & 1u);           // RNE
  return (unsigned short)(u >> 16);
}
__device__ __forceinline__ float bf2f(unsigned short u) {
  return __builtin_bit_cast(float, ((unsigned)u) << 16);
}

__device__ __forceinline__ void gld16(const void* g, const void* l) {
  __builtin_amdgcn_global_load_lds(
      (const __attribute__((address_space(1))) unsigned int*)g,
      (__attribute__((address_space(3))) unsigned int*)l, 16, 0, 0);
}

// ---------------- K_prep:
//   blocks   0..511 : per-sample prep (h, gates, Az rows incl. tail kbs)
//   blocks 512..535 : base-weight tail transpose (bwp/bwn + hb2) -> Bts idx 0..3
//   blocks 536..543 : Bts idx 4 (bias-delta row) + zero cols + colbias (one per ne)
__global__ __launch_bounds__(256, 4)
void k_prep(const float* __restrict__ hW2, unsigned short* __restrict__ Bts,
            const float* __restrict__ bwp, const float* __restrict__ bwn,
            const float* __restrict__ bbn, const float* __restrict__ hb2,
            float* __restrict__ colbias,
            const float* __restrict__ x, const float* __restrict__ cond,
            const float* __restrict__ hW1, const float* __restrict__ hb1,
            const float* __restrict__ gW1, const float* __restrict__ gb1,
            const float* __restrict__ gW2, const float* __restrict__ gb2,
            unsigned short* __restrict__ Az, float* __restrict__ gw) {
  const int bx = blockIdx.x;
  const int tid = threadIdx.x;          // 256
  __shared__ __align__(16) unsigned short Ls[64 * 256];   // 32 KiB, reused by all paths

  if (bx < 512) {                       // ---- prep path (one block per sample)
    const int b = bx;
    float* xs  = (float*)Ls;            // 256
    float* cs  = xs + INF;              // 128
    float* hs  = cs + CONDF;            // 64
    float* g1  = hs + HDIM;             // 24
    float* lsb = g1 + 24;               // 8
    float* es  = lsb + 8;               // 8
    xs[tid] = x[b * INF + tid];
    if (tid < CONDF) cs[tid] = cond[b * CONDF + tid];
    __syncthreads();
    if (tid < HDIM) {
      float acc = hb1[tid];
      for (int q = 0; q < CONDF; ++q) acc = fmaf(cs[q], hW1[q * HDIM + tid], acc);
      hs[tid] = fmaxf(acc, 0.f);
    }
    if (tid >= 64 && tid < 88) {
      const int r = tid - 64;
      float acc = gb1[r];
      for (int q = 0; q < CONDF; ++q) acc = fmaf(cs[q], gW1[q * 24 + r], acc);
      g1[r] = fmaxf(acc, 0.f);
    }
    __syncthreads();
    if (tid < NEXP) {
      float acc = gb2[tid];
      for (int j = 0; j < 24; ++j) acc = fmaf(g1[j], gW2[j * NEXP + tid], acc);
      lsb[tid] = acc;
    }
    __syncthreads();
    if (tid < NEXP) {
      float m = lsb[0];
      for (int j = 1; j < NEXP; ++j) m = fmaxf(m, lsb[j]);
      es[tid] = expf(lsb[tid] - m);
    }
    __syncthreads();
    if (tid < NEXP) {
      float s = 0.f;
      for (int j = 0; j < NEXP; ++j) s += es[j];
      gw[b * NEXP + tid] = es[tid] / s;
    }
    // z writes: 8 t-groups x 32 i-octets
    const int t0 = tid >> 5, ig = tid & 31;
#pragma unroll
    for (int tt = 0; tt < 8; ++tt) {
      const int t = tt * 8 + t0;
      const float hv = hs[t];
      us8 o;
#pragma unroll
      for (int j = 0; j < 8; ++j) o[j] = f2bf(hv * xs[ig * 8 + j]);
      *(us8*)(Az + ((size_t)(t * 4 + (ig >> 3)) * BB + b) * 64 + (ig & 7) * 8) = o;
    }
    // tail rows: kb 256..259 = x, kb 260 = h
    Az[((size_t)(256 + (tid >> 6)) * BB + b) * 64 + (tid & 63)] = f2bf(xs[tid]);
    if (tid < HDIM) Az[((size_t)260 * BB + b) * 64 + tid] = f2bf(hs[tid]);
    return;
  }

  if (bx >= 536) {                      // ---- Bts idx 4 + zeros + colbias (one per ne)
    const int ne = bx - 536;
    unsigned short* L2 = Ls;            // [64][129]
#pragma unroll
    for (int it = 0; it < 8; ++it) {
      const int f = it * 256 + tid;     // 2048 f32x4 = 8192 floats
      const int t = f >> 5, c4 = (f & 31) * 4;
      f32x4 v = *(const f32x4*)(hW2 + (size_t)t * TOTC + (size_t)ne * TPE + 49152 + c4);
#pragma unroll
      for (int j = 0; j < 4; ++j) L2[t * 129 + c4 + j] = f2bf(v[j]);
    }
    if (tid < 192)
      colbias[ne * 192 + tid] = (tid < 64) ? 0.f
        : bbn[ne * 128 + (tid - 64)] + hb2[(size_t)ne * TPE + 49152 + (tid - 64)];
    __syncthreads();
    if (tid < 128) {                    // wn cols
      const int c = tid;
#pragma unroll
      for (int t8 = 0; t8 < 8; ++t8) {
        us8 o;
#pragma unroll
        for (int j = 0; j < 8; ++j) o[j] = L2[(t8 * 8 + j) * 129 + c];
        *(us8*)(Bts + ((size_t)4 * CW + ne * 192 + 64 + c) * 64 + t8 * 8) = o;
      }
    } else {                            // wp cols: zeros
      const int cz = (tid - 128) >> 1, hf = (tid - 128) & 1;
      us8 z = (us8){0, 0, 0, 0, 0, 0, 0, 0};
#pragma unroll
      for (int t8 = 0; t8 < 4; ++t8)
        *(us8*)(Bts + ((size_t)4 * CW + ne * 192 + cz) * 64 + (hf * 4 + t8) * 8) = z;
    }
    return;
  }

  // ---- tail transpose: bwp/bwn + hb2 -> Bts idx 0..3
  const int pq = tid & 15, rg = tid >> 4, p4 = pq * 4;
  const int u = bx - 512, ne = u / 3, sec = u % 3;
  const int dst  = sec ? 128 : 64;
  const int poff = (sec == 2) ? 64 : 0;
  const int cbase = ne * 192 + sec * 64;
  const float* s1 = sec ? (bwn + (size_t)ne * INF * 128 + poff)
                        : (bwp + (size_t)ne * INF * 64);
  const float* s2 = hb2 + (size_t)ne * TPE + (sec ? 16384 : 0) + poff;
#pragma unroll
  for (int it = 0; it < 8; ++it) {
    const int i0 = rg * 2 + it * 32;
    f32x4 a1 = *(const f32x4*)(s1 + (size_t)i0 * dst + p4);
    f32x4 a2 = *(const f32x4*)(s2 + (size_t)i0 * dst + p4);
    f32x4 b1 = *(const f32x4*)(s1 + (size_t)(i0 + 1) * dst + p4);
    f32x4 b2 = *(const f32x4*)(s2 + (size_t)(i0 + 1) * dst + p4);
    const int e = i0 >> 3, q0 = i0 & 7;
#pragma unroll
    for (int j = 0; j < 4; ++j) {
      const int p = p4 + j;
      const unsigned lo = f2bf(a1[j] + a2[j]);
      const unsigned hi = f2bf(b1[j] + b2[j]);
      *(unsigned*)(&Ls[(p << 8) + (((e ^ (p >> 2)) << 3) | q0)]) = lo | (hi << 16);
    }
  }
  __syncthreads();
  us8 o[8];
#pragma unroll
  for (int it2 = 0; it2 < 8; ++it2) {
    const int of = it2 * 256 + tid;
    const int p = of >> 5, seg = of & 31;
    o[it2] = *(const us8*)(&Ls[(p << 8) + ((seg ^ (p >> 2)) << 3)]);
  }
#pragma unroll
  for (int it2 = 0; it2 < 8; ++it2) {
    const int of = it2 * 256 + tid;
    const int p = of >> 5, seg = of & 31, ib = seg >> 3, k8 = seg & 7;
    *(us8*)(Bts + ((size_t)ib * CW + cbase + p) * 64 + k8 * 8) = o[it2];
  }
}

// ---------------- K3: split-K MFMA GEMM with FUSED B transpose, software-pipelined.
// Schedule per iter t (computing tile t):
//   issue gld16 A(t+1) -> As[p^1]   (latency hides under MFMA(t))
//   issue B(t+1) global loads -> regs (drained by the barrier AFTER MFMA)
//   MFMA on As[p], Bs
//   barrier-1 (compiler drains vmcnt here, after MFMA — free)
//   commit B(t+1): cvt + ds_write -> Bs (short, LDS-only)
//   barrier-2
// As double-buffered (2x16KB), Bs single (16KB): 48KB LDS -> 3 blocks/CU.
__launch_bounds__(256, 3)
__global__ void k_gemm(const unsigned short* __restrict__ Az,
                       const float* __restrict__ hW2,
                       const unsigned short* __restrict__ Bts,
                       unsigned short* __restrict__ P) {
  const int bid = blockIdx.x;           // 0..767
  const int g  = (bid >> 5) * 8 + (bid & 7);
  const int mt = (bid >> 3) & 3;
  const int nt = g >> 4;                // 0..11
  const int s  = g & 15;                // 0..15
  const int m0 = mt * 128, n0 = nt * 128;
  // balanced split-K: first 5 splits take 17 kbs, rest 16  (5*17 + 11*16 = 261)
  const int kb0 = s * 16 + (s < 5 ? s : 5);
  const int kb1 = kb0 + 16 + (s < 5 ? 1 : 0);
  const int tid = threadIdx.x;
  __shared__ __align__(16) unsigned short As[2 * 128 * 64];   // double-buffered
  __shared__ __align__(16) unsigned short Bs[128 * 64];

  f32x4 acc[4][4];
#pragma unroll
  for (int mi = 0; mi < 4; ++mi)
#pragma unroll
    for (int ni = 0; ni < 4; ++ni) acc[mi][ni] = (f32x4){0.f, 0.f, 0.f, 0.f};

  const int wv = tid >> 6, lane = tid & 63;
  const int wm = wv >> 1, wn = wv & 1;
  const int lrow = lane & 15, quad = lane >> 4;
  const int srow = tid >> 3;            // 0..31
  const int sg0  = tid & 7;
  const int ga_a = sg0 ^ (srow & 7);    // source octet swizzle ((it*32+srow)&7 == srow&7)

  // B-staging thread constants (fused transpose path)
  const int half = tid >> 7;            // 0..1  (64-col half of the n-tile)
  const int mq   = (tid >> 3) & 15;     // 0..15 (16B col group within half)
  const int pi   = tid & 7;             // 0..7  (k row pair)
  const int ch   = n0 + half * 64;      // 64-col halves never cross wp/wn seams
  const int neb  = ch / 192;
  const int r0   = ch - neb * 192;
  const int wp   = (r0 < 64);
  const int sh   = wp ? 6 : 7;          // row stride log2 (64 or 128 floats)
  const float* Bh = hW2 + (size_t)(neb * TPE + (wp ? r0 : 16384 + (r0 - 64)) + mq * 4);
  const int rbase = half * 64 + mq * 4; // Bs row base for this thread's 4 cols

  f32x4 va[4], vb[4];                   // B prefetch regs (tail path reuses va via bit-cast)

  // ---- macros -------------------------------------------------------------
#define ISSUE_A(kbn, pn)                                                      \
  {                                                                           \
    const unsigned short* ab = Az + ((size_t)(kbn) * BB + m0) * 64;           \
    _Pragma("unroll")                                                         \
    for (int it = 0; it < 4; ++it) {                                          \
      const int r = it * 32 + srow;                                           \
      const int ldsoff = __builtin_amdgcn_readfirstlane(                      \
          (pn) * 16384 + it * 4096 + wv * 1024);                              \
      gld16(ab + (size_t)r * 64 + ga_a * 8, (const char*)As + ldsoff);        \
    }                                                                         \
  }

#define ISSUE_B(kbn)                                                          \
  {                                                                           \
    if ((kbn) < 256) {                                                        \
      const float* Br = Bh + (size_t)((kbn) >> 2) * TOTC;                     \
      const int i0 = ((kbn) & 3) * 64;                                        \
      _Pragma("unroll")                                                       \
      for (int it = 0; it < 4; ++it) {                                        \
        const int ko = i0 + pi * 2 + it * 16;                                 \
        va[it] = *(const f32x4*)(Br + ((size_t)ko << sh));                    \
        vb[it] = *(const f32x4*)(Br + ((size_t)(ko + 1) << sh));              \
      }                                                                       \
    } else {                                                                  \
      const unsigned short* bbp = Bts + ((size_t)((kbn) - 256) * CW + n0) * 64;\
      _Pragma("unroll")                                                       \
      for (int it = 0; it < 4; ++it)                                          \
        va[it] = __builtin_bit_cast(                                          \
            f32x4, *(const us8*)(bbp + (size_t)(it * 32 + srow) * 64 + ga_a * 8));\
    }                                                                         \
  }

#define COMMIT_B(kbn)                                                         \
  {                                                                           \
    if ((kbn) < 256) {                                                        \
      _Pragma("unroll")                                                       \
      for (int it = 0; it < 4; ++it) {                                        \
        const int gg = (pi >> 2) + it * 2;                                    \
        _Pragma("unroll")                                                     \
        for (int j = 0; j < 4; ++j) {                                         \
          const int rl = rbase + j;                                           \
          const unsigned lo = f2bf(va[it][j]), hi = f2bf(vb[it][j]);          \
          *(unsigned*)((char*)Bs + rl * 128 + ((gg ^ (rl & 7)) << 4) +        \
                       ((pi & 3) << 2)) = lo | (hi << 16);                    \
        }                                                                     \
      }                                                                       \
    } else {                                                                  \
      _Pragma("unroll")                                                       \
      for (int it = 0; it < 4; ++it)                                          \
        *(us8*)((char*)Bs + it * 4096 + tid * 16) =                           \
            __builtin_bit_cast(us8, va[it]);                                  \
    }                                                                         \
  }
  // -------------------------------------------------------------------------

  // prologue: stage tile kb0 (kb0 <= 245, always fused path for B)
  ISSUE_A(kb0, 0);
  ISSUE_B(kb0);
  COMMIT_B(kb0);                        // vmcnt wait on va/vb implied
  __syncthreads();                      // drains A gld16 too

  for (int t = kb0; t < kb1; ++t) {
    const int p = (t - kb0) & 1;
    const bool pf = (t + 1 < kb1);
    if (pf) {
      ISSUE_A(t + 1, p ^ 1);            // hides under MFMA(t)
      ISSUE_B(t + 1);                   // drained by barrier-1 (post-MFMA)
    }
    // ---- MFMA on As[p], Bs
    const unsigned short* Asp = As + p * (128 * 64);
#pragma unroll
    for (int kh = 0; kh < 2; ++kh) {
      bf16x8 af[4], bfr[4];
#pragma unroll
      for (int mi = 0; mi < 4; ++mi) {
        const int r = wm * 64 + mi * 16 + lrow;
        const int ga = (kh * 4 + quad) ^ (r & 7);
        af[mi] = *(const bf16x8*)(Asp + r * 64 + ga * 8);
      }
#pragma unroll
      for (int ni = 0; ni < 4; ++ni) {
        const int r = wn * 64 + ni * 16 + lrow;
        const int ga = (kh * 4 + quad) ^ (r & 7);
        bfr[ni] = *(const bf16x8*)(Bs + r * 64 + ga * 8);
      }
#pragma unroll
      for (int mi = 0; mi < 4; ++mi)
#pragma unroll
        for (int ni = 0; ni < 4; ++ni)
          acc[mi][ni] = __builtin_amdgcn_mfma_f32_16x16x32_bf16(af[mi], bfr[ni], acc[mi][ni], 0, 0, 0);
    }
    __syncthreads();                    // barrier-1: Bs reads done; loads drained here
    if (pf) {
      COMMIT_B(t + 1);                  // short LDS-only phase
      __syncthreads();                  // barrier-2: Bs(t+1) visible
    }
  }
#undef ISSUE_A
#undef ISSUE_B
#undef COMMIT_B

  // write bf16 partials: D row = quad*4+reg, col = lane&15
#pragma unroll
  for (int mi = 0; mi < 4; ++mi) {
    const int row0 = m0 + wm * 64 + mi * 16 + quad * 4;
#pragma unroll
    for (int ni = 0; ni < 4; ++ni) {
      const int col = n0 + wn * 64 + ni * 16 + lrow;
      unsigned short* pp = P + ((size_t)s * BB + row0) * CW + col;
#pragma unroll
      for (int r = 0; r < 4; ++r) pp[(size_t)r * CW] = f2bf(acc[mi][ni][r]);
    }
  }
}

// ---------------- K4: epilogue — sum bf16 split-K partials, cos/sin/relu, gated expert sum
__global__ void k_epi(const unsigned short* __restrict__ P, const float* __restrict__ gw,
                      const float* __restrict__ colbias, float* __restrict__ out) {
  const int b = blockIdx.x;
  const int r = threadIdx.x;            // 192: wave0 = wp cols, waves1-2 = wn cols
  __shared__ float gws[NEXP];
  if (r < NEXP) gws[r] = gw[b * NEXP + r];
  __syncthreads();
  float co = 0.f, si = 0.f, nc = 0.f;
  for (int n = 0; n < NEXP; ++n) {
    const int c = n * 192 + r;
    float v = colbias[c];
#pragma unroll
    for (int s2 = 0; s2 < NSPLIT; ++s2) v += bf2f(P[((size_t)s2 * BB + b) * CW + c]);
    const float g = gws[n];
    if (r < 64) { co = fmaf(g, cosf(v), co); si = fmaf(g, sinf(v), si); }
    else        { nc = fmaf(g, fmaxf(v, 0.f), nc); }
  }
  if (r < 64) { out[b * 256 + r] = co; out[b * 256 + 64 + r] = si; }
  else        { out[b * 256 + 128 + (r - 64)] = nc; }
}

extern "C" void kernel_launch(void* const* d_in, const int* in_sizes, int n_in,
                              void* d_out, int out_size, void* d_ws, size_t ws_size,
                              hipStream_t stream) {
  const float* x    = (const float*)d_in[0];
  const float* cond = (const float*)d_in[1];
  const float* bwp  = (const float*)d_in[2];
  const float* bwn  = (const float*)d_in[3];
  const float* bbn  = (const float*)d_in[4];
  const float* hW1  = (const float*)d_in[5];
  const float* hb1  = (const float*)d_in[6];
  const float* hW2  = (const float*)d_in[7];
  const float* hb2  = (const float*)d_in[8];
  const float* gW1  = (const float*)d_in[9];
  const float* gb1  = (const float*)d_in[10];
  const float* gW2  = (const float*)d_in[11];
  const float* gb2  = (const float*)d_in[12];
  float* out = (float*)d_out;
  char* ws = (char*)d_ws;

  unsigned short* Az  = (unsigned short*)(ws + AZ_OFF);
  unsigned short* Bts = (unsigned short*)(ws + BTS_OFF);
  unsigned short* Pp  = (unsigned short*)(ws + P_OFF);
  float* gw      = (float*)(ws + GW_OFF);
  float* colbias = (float*)(ws + CB_OFF);

  hipLaunchKernelGGL(k_prep, dim3(544), dim3(256), 0, stream,
                     hW2, Bts, bwp, bwn, bbn, hb2, colbias,
                     x, cond, hW1, hb1, gW1, gb1, gW2, gb2, Az, gw);
  hipLaunchKernelGGL(k_gemm, dim3(768), dim3(256), 0, stream, Az, hW2, Bts, Pp);
  hipLaunchKernelGGL(k_epi, dim3(BB), dim3(192), 0, stream, Pp, gw, colbias, out);
}

// Round 5
// 213.934 us; speedup vs baseline: 1.1059x; 1.0752x over previous
//
#include <hip/hip_runtime.h>
#include <math.h>

// Problem constants
#define BB     512
#define INF    256
#define CONDF  128
#define NEXP   8
#define HDIM   64
#define TPE    49280      // IN*DP + IN*DN + DN
#define TOTC   394240     // N*TPE
#define NSPLIT 16
#define CW     1536       // GEMM columns: 8 experts * (64 wp + 128 wn)
#define KB     261        // K blocks of 64: 64*4 main + 5 tail (16704 total K)

// Workspace layout (bytes). Total ~93.6 MB.
#define AZ_OFF 0u                     // ushort [261][512][64]  = 17,104,896
#define BT_OFF 17104896u              // ushort [261][1536][64] = 51,314,688
#define P_OFF  68419584u              // ushort [16][512][1536] = 25,165,824 (bf16 partials)
#define GW_OFF 93585408u              // float  [512][8]
#define CB_OFF 93601792u              // float  [1536]

typedef __bf16          bf16x8 __attribute__((ext_vector_type(8)));
typedef unsigned short  us8    __attribute__((ext_vector_type(8)));
typedef float           f32x4  __attribute__((ext_vector_type(4)));

__device__ __forceinline__ unsigned short f2bf(float f) {
  unsigned u = __builtin_bit_cast(unsigned, f);
  u += 0x7fffu + ((u >> 16) & 1u);           // RNE
  return (unsigned short)(u >> 16);
}
__device__ __forceinline__ float bf2f(unsigned short u) {
  return __builtin_bit_cast(float, ((unsigned)u) << 16);
}

__device__ __forceinline__ void gld16(const void* g, const void* l) {
  __builtin_amdgcn_global_load_lds(
      (const __attribute__((address_space(1))) unsigned int*)g,
      (__attribute__((address_space(3))) unsigned int*)l, 16, 0, 0);
}

// ---------------- K2 (merged):
//   blocks    0..1535 : hW2 transpose (one per (t, ne, sec)) -> Bt kb 0..255
//   blocks 1536..2047 : per-sample prep (h, gates, Az rows)
//   blocks 2048..2071 : base-weight tail transpose (bwp/bwn + hb2) -> Bt kb 256..259
//   blocks 2072..2079 : kb 260 (bias-delta row), zero cols, colbias (one per ne)
__global__ __launch_bounds__(256, 4)
void k_bt(const float* __restrict__ hW2, unsigned short* __restrict__ Bt,
          const float* __restrict__ bwp, const float* __restrict__ bwn,
          const float* __restrict__ bbn, const float* __restrict__ hb2,
          float* __restrict__ colbias,
          const float* __restrict__ x, const float* __restrict__ cond,
          const float* __restrict__ hW1, const float* __restrict__ hb1,
          const float* __restrict__ gW1, const float* __restrict__ gb1,
          const float* __restrict__ gW2, const float* __restrict__ gb2,
          unsigned short* __restrict__ Az, float* __restrict__ gw) {
  const int bx = blockIdx.x;
  const int tid = threadIdx.x;          // 256
  __shared__ __align__(16) unsigned short Ls[64 * 256];   // 32 KiB, reused by all paths

  if (bx >= 2072) {                     // ---- kb 260 + zeros + colbias (one block per ne)
    const int ne = bx - 2072;
    unsigned short* L2 = Ls;            // [64][129]
#pragma unroll
    for (int it = 0; it < 8; ++it) {
      const int f = it * 256 + tid;     // 2048 f32x4 = 8192 floats
      const int t = f >> 5, c4 = (f & 31) * 4;
      f32x4 v = *(const f32x4*)(hW2 + (size_t)t * TOTC + (size_t)ne * TPE + 49152 + c4);
#pragma unroll
      for (int j = 0; j < 4; ++j) L2[t * 129 + c4 + j] = f2bf(v[j]);
    }
    if (tid < 192)
      colbias[ne * 192 + tid] = (tid < 64) ? 0.f
        : bbn[ne * 128 + (tid - 64)] + hb2[(size_t)ne * TPE + 49152 + (tid - 64)];
    __syncthreads();
    if (tid < 128) {                    // wn cols: Bt[260][ne*192+64+c][t] = hW2[t][bias+c]
      const int c = tid;
#pragma unroll
      for (int t8 = 0; t8 < 8; ++t8) {
        us8 o;
#pragma unroll
        for (int j = 0; j < 8; ++j) o[j] = L2[(t8 * 8 + j) * 129 + c];
        *(us8*)(Bt + ((size_t)260 * CW + ne * 192 + 64 + c) * 64 + t8 * 8) = o;
      }
    } else {                            // wp cols: zeros
      const int cz = (tid - 128) >> 1, hf = (tid - 128) & 1;
      us8 z = (us8){0, 0, 0, 0, 0, 0, 0, 0};
#pragma unroll
      for (int t8 = 0; t8 < 4; ++t8)
        *(us8*)(Bt + ((size_t)260 * CW + ne * 192 + cz) * 64 + (hf * 4 + t8) * 8) = z;
    }
    return;
  }

  if (bx >= 1536 && bx < 2048) {        // ---- prep path (one block per sample)
    const int b = bx - 1536;
    float* xs  = (float*)Ls;            // 256
    float* cs  = xs + INF;              // 128
    float* hs  = cs + CONDF;            // 64
    float* g1  = hs + HDIM;             // 24
    float* lsb = g1 + 24;               // 8
    float* es  = lsb + 8;               // 8
    xs[tid] = x[b * INF + tid];
    if (tid < CONDF) cs[tid] = cond[b * CONDF + tid];
    __syncthreads();
    if (tid < HDIM) {
      float acc = hb1[tid];
      for (int q = 0; q < CONDF; ++q) acc = fmaf(cs[q], hW1[q * HDIM + tid], acc);
      hs[tid] = fmaxf(acc, 0.f);
    }
    if (tid >= 64 && tid < 88) {
      const int r = tid - 64;
      float acc = gb1[r];
      for (int q = 0; q < CONDF; ++q) acc = fmaf(cs[q], gW1[q * 24 + r], acc);
      g1[r] = fmaxf(acc, 0.f);
    }
    __syncthreads();
    if (tid < NEXP) {
      float acc = gb2[tid];
      for (int j = 0; j < 24; ++j) acc = fmaf(g1[j], gW2[j * NEXP + tid], acc);
      lsb[tid] = acc;
    }
    __syncthreads();
    if (tid < NEXP) {
      float m = lsb[0];
      for (int j = 1; j < NEXP; ++j) m = fmaxf(m, lsb[j]);
      es[tid] = expf(lsb[tid] - m);
    }
    __syncthreads();
    if (tid < NEXP) {
      float s = 0.f;
      for (int j = 0; j < NEXP; ++j) s += es[j];
      gw[b * NEXP + tid] = es[tid] / s;
    }
    // z writes: 8 t-groups x 32 i-octets
    const int t0 = tid >> 5, ig = tid & 31;
#pragma unroll
    for (int tt = 0; tt < 8; ++tt) {
      const int t = tt * 8 + t0;
      const float hv = hs[t];
      us8 o;
#pragma unroll
      for (int j = 0; j < 8; ++j) o[j] = f2bf(hv * xs[ig * 8 + j]);
      *(us8*)(Az + ((size_t)(t * 4 + (ig >> 3)) * BB + b) * 64 + (ig & 7) * 8) = o;
    }
    // tail rows: kb 256..259 = x, kb 260 = h
    Az[((size_t)(256 + (tid >> 6)) * BB + b) * 64 + (tid & 63)] = f2bf(xs[tid]);
    if (tid < HDIM) Az[((size_t)260 * BB + b) * 64 + tid] = f2bf(hs[tid]);
    return;
  }

  // ---- transpose paths (main hW2 and base-weight tail) share phase 2
  const int pq = tid & 15, rg = tid >> 4, p4 = pq * 4;
  int kbBase, cbase;

  if (bx < 1536) {                      // main: hW2 row t, expert ne, section sec
    const int t = bx / 24, rem = bx % 24, ne = rem / 3, sec = rem % 3;
    const int dst  = sec ? 128 : 64;
    const int poff = (sec == 2) ? 64 : 0;
    kbBase = t * 4;
    cbase  = ne * 192 + sec * 64;
    const float* src = hW2 + (size_t)t * TOTC + (size_t)ne * TPE
                       + (sec ? 16384 : 0) + poff + p4;
    // phase 1: 16 loads ALL in flight, then convert+pack+LDS
    f32x4 va[8], vb[8];
#pragma unroll
    for (int it = 0; it < 8; ++it) {
      const int i0 = rg * 2 + it * 32;
      va[it] = *(const f32x4*)(src + (size_t)i0 * dst);
      vb[it] = *(const f32x4*)(src + (size_t)(i0 + 1) * dst);
    }
#pragma unroll
    for (int it = 0; it < 8; ++it) {
      const int i0 = rg * 2 + it * 32;
      const int e = i0 >> 3, q0 = i0 & 7;            // q0 even
#pragma unroll
      for (int j = 0; j < 4; ++j) {
        const int p = p4 + j;
        const unsigned lo = f2bf(va[it][j]), hi = f2bf(vb[it][j]);
        *(unsigned*)(&Ls[(p << 8) + (((e ^ (p >> 2)) << 3) | q0)]) = lo | (hi << 16);
      }
    }
  } else {                              // tail: bwp/bwn + hb2 -> kb 256..259
    const int u = bx - 2048, ne = u / 3, sec = u % 3;
    const int dst  = sec ? 128 : 64;
    const int poff = (sec == 2) ? 64 : 0;
    kbBase = 256;
    cbase  = ne * 192 + sec * 64;
    const float* s1 = sec ? (bwn + (size_t)ne * INF * 128 + poff)
                          : (bwp + (size_t)ne * INF * 64);
    const float* s2 = hb2 + (size_t)ne * TPE + (sec ? 16384 : 0) + poff;
#pragma unroll
    for (int it = 0; it < 8; ++it) {
      const int i0 = rg * 2 + it * 32;
      f32x4 a1 = *(const f32x4*)(s1 + (size_t)i0 * dst + p4);
      f32x4 a2 = *(const f32x4*)(s2 + (size_t)i0 * dst + p4);
      f32x4 b1 = *(const f32x4*)(s1 + (size_t)(i0 + 1) * dst + p4);
      f32x4 b2 = *(const f32x4*)(s2 + (size_t)(i0 + 1) * dst + p4);
      const int e = i0 >> 3, q0 = i0 & 7;
#pragma unroll
      for (int j = 0; j < 4; ++j) {
        const int p = p4 + j;
        const unsigned lo = f2bf(a1[j] + a2[j]);
        const unsigned hi = f2bf(b1[j] + b2[j]);
        *(unsigned*)(&Ls[(p << 8) + (((e ^ (p >> 2)) << 3) | q0)]) = lo | (hi << 16);
      }
    }
  }
  __syncthreads();
  // phase 2: buffered b128 reads, then store burst (8-lane 128B-contiguous chunks)
  us8 o[8];
#pragma unroll
  for (int it2 = 0; it2 < 8; ++it2) {
    const int of = it2 * 256 + tid;
    const int p = of >> 5, seg = of & 31;
    o[it2] = *(const us8*)(&Ls[(p << 8) + ((seg ^ (p >> 2)) << 3)]);
  }
#pragma unroll
  for (int it2 = 0; it2 < 8; ++it2) {
    const int of = it2 * 256 + tid;
    const int p = of >> 5, seg = of & 31, ib = seg >> 3, k8 = seg & 7;
    *(us8*)(Bt + ((size_t)(kbBase + ib) * CW + cbase + p) * 64 + k8 * 8) = o[it2];
  }
}

// ---------------- K3: split-K MFMA GEMM (round-1 proven version, from bf16 Bt).
// Block 128m x 128n, 768 blocks = 3/CU.  XCD co-location swizzle:
//   id = (g>>3)*32 + (g&7) + mt*8   where g = nt*16+s
__launch_bounds__(256, 3)
__global__ void k_gemm(const unsigned short* __restrict__ Az,
                       const unsigned short* __restrict__ Bt,
                       unsigned short* __restrict__ P) {
  const int bid = blockIdx.x;           // 0..767
  const int g  = (bid >> 5) * 8 + (bid & 7);
  const int mt = (bid >> 3) & 3;
  const int nt = g >> 4;                // 0..11
  const int s  = g & 15;                // 0..15
  const int m0 = mt * 128, n0 = nt * 128;
  // balanced split-K: first 5 splits take 17 kbs, rest 16  (5*17 + 11*16 = 261)
  const int kb0 = s * 16 + (s < 5 ? s : 5);
  const int kb1 = kb0 + 16 + (s < 5 ? 1 : 0);
  const int tid = threadIdx.x;
  __shared__ __align__(16) unsigned short As[128 * 64];
  __shared__ __align__(16) unsigned short Bs[128 * 64];

  f32x4 acc[4][4];
#pragma unroll
  for (int mi = 0; mi < 4; ++mi)
#pragma unroll
    for (int ni = 0; ni < 4; ++ni) acc[mi][ni] = (f32x4){0.f, 0.f, 0.f, 0.f};

  const int wv = tid >> 6, lane = tid & 63;
  const int wm = wv >> 1, wn = wv & 1;
  const int lrow = lane & 15, quad = lane >> 4;
  const int srow = tid >> 3;            // 0..31
  const int sg0  = tid & 7;

  const unsigned short* ab = Az + ((size_t)kb0 * BB + m0) * 64;
  const unsigned short* bb = Bt + ((size_t)kb0 * CW + n0) * 64;

  for (int kb = kb0; kb < kb1; ++kb) {
#pragma unroll
    for (int it = 0; it < 4; ++it) {
      const int r = it * 32 + srow;
      const int ga = sg0 ^ (r & 7);
      const int ldsoff = __builtin_amdgcn_readfirstlane(it * 4096 + wv * 1024);
      gld16(ab + (size_t)r * 64 + ga * 8, (const char*)As + ldsoff);
      gld16(bb + (size_t)r * 64 + ga * 8, (const char*)Bs + ldsoff);
    }
    __syncthreads();
#pragma unroll
    for (int kh = 0; kh < 2; ++kh) {
      bf16x8 af[4], bfr[4];
#pragma unroll
      for (int mi = 0; mi < 4; ++mi) {
        const int r = wm * 64 + mi * 16 + lrow;
        const int ga = (kh * 4 + quad) ^ (r & 7);
        af[mi] = *(const bf16x8*)(As + r * 64 + ga * 8);
      }
#pragma unroll
      for (int ni = 0; ni < 4; ++ni) {
        const int r = wn * 64 + ni * 16 + lrow;
        const int ga = (kh * 4 + quad) ^ (r & 7);
        bfr[ni] = *(const bf16x8*)(Bs + r * 64 + ga * 8);
      }
#pragma unroll
      for (int mi = 0; mi < 4; ++mi)
#pragma unroll
        for (int ni = 0; ni < 4; ++ni)
          acc[mi][ni] = __builtin_amdgcn_mfma_f32_16x16x32_bf16(af[mi], bfr[ni], acc[mi][ni], 0, 0, 0);
    }
    __syncthreads();
    ab += (size_t)BB * 64;
    bb += (size_t)CW * 64;
  }

  // write bf16 partials: D row = quad*4+reg, col = lane&15
#pragma unroll
  for (int mi = 0; mi < 4; ++mi) {
    const int row0 = m0 + wm * 64 + mi * 16 + quad * 4;
#pragma unroll
    for (int ni = 0; ni < 4; ++ni) {
      const int col = n0 + wn * 64 + ni * 16 + lrow;
      unsigned short* pp = P + ((size_t)s * BB + row0) * CW + col;
#pragma unroll
      for (int r = 0; r < 4; ++r) pp[(size_t)r * CW] = f2bf(acc[mi][ni][r]);
    }
  }
}

// ---------------- K4: epilogue (vectorized). One block per sample, 256 threads.
// Phase 1 (threads 0..191): thread owns expert n = t/24, 8 cols rr = (t%24)*8.
//   us8 loads of P (wave reads 1 KB contiguous per split, 16 splits in flight),
//   gated cos/sin/relu into LDS [expert][slot].
// Phase 2 (all 256): out[b][r] = sum over 8 experts.
__global__ __launch_bounds__(256, 8)
void k_epi(const unsigned short* __restrict__ P, const float* __restrict__ gw,
           const float* __restrict__ colbias, float* __restrict__ out) {
  const int b = blockIdx.x;
  const int t = threadIdx.x;            // 256
  __shared__ float cc[NEXP][64];
  __shared__ float ss[NEXP][64];
  __shared__ float nn[NEXP][128];
  __shared__ float gws[NEXP];
  if (t < NEXP) gws[t] = gw[b * NEXP + t];
  __syncthreads();
  if (t < 192) {
    const int n = t / 24, rr = (t % 24) * 8;
    const int c = n * 192 + rr;
    float acc[8];
#pragma unroll
    for (int j = 0; j < 8; ++j) acc[j] = colbias[c + j];
#pragma unroll
    for (int s2 = 0; s2 < NSPLIT; ++s2) {
      us8 v = *(const us8*)(P + ((size_t)s2 * BB + b) * CW + c);
#pragma unroll
      for (int j = 0; j < 8; ++j) acc[j] += bf2f(v[j]);
    }
    const float gv = gws[n];
    if (rr < 64) {
#pragma unroll
      for (int j = 0; j < 8; ++j) {
        cc[n][rr + j] = gv * cosf(acc[j]);
        ss[n][rr + j] = gv * sinf(acc[j]);
      }
    } else {
#pragma unroll
      for (int j = 0; j < 8; ++j)
        nn[n][rr - 64 + j] = gv * fmaxf(acc[j], 0.f);
    }
  }
  __syncthreads();
  float sum = 0.f;
  if (t < 64) {
#pragma unroll
    for (int n = 0; n < NEXP; ++n) sum += cc[n][t];
  } else if (t < 128) {
#pragma unroll
    for (int n = 0; n < NEXP; ++n) sum += ss[n][t - 64];
  } else {
#pragma unroll
    for (int n = 0; n < NEXP; ++n) sum += nn[n][t - 128];
  }
  out[b * 256 + t] = sum;
}

extern "C" void kernel_launch(void* const* d_in, const int* in_sizes, int n_in,
                              void* d_out, int out_size, void* d_ws, size_t ws_size,
                              hipStream_t stream) {
  const float* x    = (const float*)d_in[0];
  const float* cond = (const float*)d_in[1];
  const float* bwp  = (const float*)d_in[2];
  const float* bwn  = (const float*)d_in[3];
  const float* bbn  = (const float*)d_in[4];
  const float* hW1  = (const float*)d_in[5];
  const float* hb1  = (const float*)d_in[6];
  const float* hW2  = (const float*)d_in[7];
  const float* hb2  = (const float*)d_in[8];
  const float* gW1  = (const float*)d_in[9];
  const float* gb1  = (const float*)d_in[10];
  const float* gW2  = (const float*)d_in[11];
  const float* gb2  = (const float*)d_in[12];
  float* out = (float*)d_out;
  char* ws = (char*)d_ws;

  unsigned short* Az = (unsigned short*)(ws + AZ_OFF);
  unsigned short* Bt = (unsigned short*)(ws + BT_OFF);
  unsigned short* Pp = (unsigned short*)(ws + P_OFF);
  float* gw      = (float*)(ws + GW_OFF);
  float* colbias = (float*)(ws + CB_OFF);

  hipLaunchKernelGGL(k_bt, dim3(2080), dim3(256), 0, stream,
                     hW2, Bt, bwp, bwn, bbn, hb2, colbias,
                     x, cond, hW1, hb1, gW1, gb1, gW2, gb2, Az, gw);
  hipLaunchKernelGGL(k_gemm, dim3(768), dim3(256), 0, stream, Az, Bt, Pp);
  hipLaunchKernelGGL(k_epi, dim3(BB), dim3(256), 0, stream, Pp, gw, colbias, out);
}